// Round 1
// baseline (357.418 us; speedup 1.0000x reference)
//
#include <hip/hip_runtime.h>

#define DIM 32

__global__ void deg_kernel(const int* __restrict__ dst, float* __restrict__ deg, int E) {
    int e = blockIdx.x * blockDim.x + threadIdx.x;
    if (e < E) atomicAdd(&deg[dst[e]], 1.0f);
}

__global__ void dis_kernel(const float* __restrict__ deg, float* __restrict__ dis, int n) {
    int i = blockIdx.x * blockDim.x + threadIdx.x;
    if (i < n) dis[i] = rsqrtf(deg[i] + 1.0f);  // +1 self-loop; always > 0
}

__global__ void gemm_kernel(const float* __restrict__ x, const float* __restrict__ W,
                            float* __restrict__ h, int n) {
    __shared__ float Ws[DIM * DIM];
    int tid = threadIdx.x;
    for (int i = tid; i < DIM * DIM; i += blockDim.x) Ws[i] = W[i];
    __syncthreads();
    int row = blockIdx.x * (blockDim.x / DIM) + (tid >> 5);
    int col = tid & 31;
    if (row < n) {
        const float* xr = x + row * DIM;
        float s = 0.f;
#pragma unroll
        for (int k = 0; k < DIM; ++k) s += xr[k] * Ws[k * DIM + col];
        h[row * DIM + col] = s;
    }
}

__global__ void scatter_kernel(const int* __restrict__ src, const int* __restrict__ dst,
                               const float* __restrict__ dis, const float* __restrict__ h,
                               float* __restrict__ accum, int E) {
    int t = blockIdx.x * blockDim.x + threadIdx.x;
    int e = t >> 5;
    int f = t & 31;
    if (e < E) {
        int s = src[e], d = dst[e];
        float nrm = dis[s] * dis[d];
        atomicAdd(&accum[d * DIM + f], h[s * DIM + f] * nrm);
    }
}

__global__ void final_kernel(const float* __restrict__ accum, const float* __restrict__ h,
                             const float* __restrict__ dis, const float* __restrict__ b,
                             float* __restrict__ out, int n) {
    int t = blockIdx.x * blockDim.x + threadIdx.x;
    int i = t >> 5;
    int f = t & 31;
    if (i >= n) return;
    float di = dis[i];
    float v = accum[i * DIM + f] + h[i * DIM + f] * di * di + b[f];
    float s1 = v, s2 = v * v;
#pragma unroll
    for (int off = 16; off > 0; off >>= 1) {
        s1 += __shfl_xor(s1, off, 32);
        s2 += __shfl_xor(s2, off, 32);
    }
    float mean = s1 * (1.0f / 32.0f);
    float var = s2 * (1.0f / 32.0f) - mean * mean;
    var = fmaxf(var, 0.0f);
    float o = (v - mean) * rsqrtf(var + 1e-6f);
    out[i * DIM + f] = (o >= 0.f) ? o : 0.01f * o;
}

extern "C" void kernel_launch(void* const* d_in, const int* in_sizes, int n_in,
                              void* d_out, int out_size, void* d_ws, size_t ws_size,
                              hipStream_t stream) {
    const float* x = (const float*)d_in[0];
    const int* edge_index = (const int*)d_in[1];
    const float* W = (const float*)d_in[2];
    const float* b = (const float*)d_in[3];
    float* out = (float*)d_out;

    const int N = in_sizes[0] / DIM;      // 100000
    const int E = in_sizes[1] / 2;        // 1600000
    const int* src = edge_index;          // edge_index[0, :]
    const int* dst = edge_index + E;      // edge_index[1, :]

    float* accum = (float*)d_ws;              // N*DIM
    float* h     = accum + (size_t)N * DIM;   // N*DIM
    float* deg   = h + (size_t)N * DIM;       // N
    float* dis   = deg + N;                   // N

    hipMemsetAsync(accum, 0, (size_t)N * DIM * sizeof(float), stream);
    hipMemsetAsync(deg, 0, (size_t)N * sizeof(float), stream);

    deg_kernel<<<(E + 255) / 256, 256, 0, stream>>>(dst, deg, E);
    dis_kernel<<<(N + 255) / 256, 256, 0, stream>>>(deg, dis, N);
    gemm_kernel<<<(N + 7) / 8, 256, 0, stream>>>(x, W, h, N);
    scatter_kernel<<<(E + 7) / 8, 256, 0, stream>>>(src, dst, dis, h, accum, E);
    final_kernel<<<(N + 7) / 8, 256, 0, stream>>>(accum, h, dis, b, out, N);
}